// Round 2
// baseline (742.598 us; speedup 1.0000x reference)
//
#include <hip/hip_runtime.h>

#define D 64
#define EDIM 16
#define CHUNK 1024   // counts-scan chunk size

// ---------------------------------------------------------------------------
// Phase 1: histogram of dst  (cnt[d] = degree of node d)
// ---------------------------------------------------------------------------
__global__ __launch_bounds__(256) void hist_kernel(
    const int* __restrict__ dst, int* __restrict__ cnt, int E)
{
    int i = blockIdx.x * blockDim.x + threadIdx.x;
    int stride = gridDim.x * blockDim.x;
    for (; i < E; i += stride) atomicAdd(&cnt[dst[i]], 1);
}

// ---------------------------------------------------------------------------
// Phase 2a: per-chunk sums (CHUNK counts per block)
// ---------------------------------------------------------------------------
__global__ __launch_bounds__(256) void chunk_sum_kernel(
    const int* __restrict__ cnt, int* __restrict__ bsum, int N)
{
    __shared__ int red[256];
    const int base = blockIdx.x * CHUNK;
    const int t = threadIdx.x;
    int s = 0;
#pragma unroll
    for (int r = 0; r < 4; ++r) {
        int idx = base + t + r * 256;
        if (idx < N) s += cnt[idx];
    }
    red[t] = s; __syncthreads();
    for (int off = 128; off > 0; off >>= 1) {
        if (t < off) red[t] += red[t + off];
        __syncthreads();
    }
    if (t == 0) bsum[blockIdx.x] = red[0];
}

// ---------------------------------------------------------------------------
// Phase 2b: exclusive scan of chunk sums (single block; nchunks <= 256)
// ---------------------------------------------------------------------------
__global__ __launch_bounds__(256) void scan_chunksums_kernel(
    int* __restrict__ bsum, int nchunks, int* __restrict__ row_start,
    int N, int E)
{
    __shared__ int lds[256];
    const int t = threadIdx.x;
    const int v = (t < nchunks) ? bsum[t] : 0;
    lds[t] = v; __syncthreads();
    for (int off = 1; off < 256; off <<= 1) {
        int add = (t >= off) ? lds[t - off] : 0;
        __syncthreads();
        lds[t] += add;
        __syncthreads();
    }
    if (t < nchunks) bsum[t] = lds[t] - v;   // exclusive
    if (t == 0) row_start[N] = E;
}

// ---------------------------------------------------------------------------
// Phase 2c: per-chunk exclusive scan -> row_start (and cursor copy)
// ---------------------------------------------------------------------------
__global__ __launch_bounds__(256) void chunk_scan_kernel(
    const int* __restrict__ cnt, const int* __restrict__ bsum,
    int* __restrict__ row_start, int* __restrict__ cursor, int N)
{
    __shared__ int lds[256];
    const int base = blockIdx.x * CHUNK;
    const int t = threadIdx.x;
    int v[4]; int s = 0;
#pragma unroll
    for (int r = 0; r < 4; ++r) {
        int idx = base + t * 4 + r;
        v[r] = (idx < N) ? cnt[idx] : 0;
        s += v[r];
    }
    lds[t] = s; __syncthreads();
    for (int off = 1; off < 256; off <<= 1) {
        int add = (t >= off) ? lds[t - off] : 0;
        __syncthreads();
        lds[t] += add;
        __syncthreads();
    }
    int run = bsum[blockIdx.x] + (lds[t] - s);   // exclusive within grid
#pragma unroll
    for (int r = 0; r < 4; ++r) {
        int idx = base + t * 4 + r;
        if (idx < N) { row_start[idx] = run; cursor[idx] = run; }
        run += v[r];
    }
}

// ---------------------------------------------------------------------------
// Phase 3: scatter edge ids into CSR order
// ---------------------------------------------------------------------------
__global__ __launch_bounds__(256) void scatter_kernel(
    const int* __restrict__ dst, int* __restrict__ cursor,
    int* __restrict__ eid, int E)
{
    int i = blockIdx.x * blockDim.x + threadIdx.x;
    int stride = gridDim.x * blockDim.x;
    for (; i < E; i += stride) {
        int d = dst[i];
        int p = atomicAdd(&cursor[d], 1);
        eid[p] = i;
    }
}

// ---------------------------------------------------------------------------
// Phase 4: gather-aggregate. One wave per node; lane j owns column j.
//   h[n] = x[n] + sum_{e in CSR(n)} relu(x[src_e] + edge_attr_e @ W_edge + b)
// No atomics: each output row written exactly once. 2-edge manual ILP to
// double the number of in-flight dependent load chains.
// ---------------------------------------------------------------------------
__global__ __launch_bounds__(256) void gather_kernel(
    const float* __restrict__ x,
    const int*   __restrict__ src,
    const float* __restrict__ edge_attr,
    const float* __restrict__ W_edge,
    const float* __restrict__ b_edge,
    const int*   __restrict__ row_start,
    const int*   __restrict__ eid,
    float*       __restrict__ h,
    int N)
{
    const int lane   = threadIdx.x & 63;
    const int wave   = blockIdx.x * 4 + (threadIdx.x >> 6);
    const int nwaves = gridDim.x * 4;

    float we[EDIM];
#pragma unroll
    for (int k = 0; k < EDIM; ++k) we[k] = W_edge[k * D + lane];
    const float be = b_edge[lane];

    for (int n = wave; n < N; n += nwaves) {
        const int e0 = row_start[n];
        const int e1 = row_start[n + 1];
        float acc = 0.0f;

        int e = e0;
        for (; e + 1 < e1; e += 2) {
            const int i0 = eid[e], i1 = eid[e + 1];
            const int s0 = src[i0], s1 = src[i1];
            const float4* a = (const float4*)(edge_attr + (size_t)i0 * EDIM);
            const float4* b = (const float4*)(edge_attr + (size_t)i1 * EDIM);
            const float xv0 = x[(size_t)s0 * D + lane];
            const float xv1 = x[(size_t)s1 * D + lane];
            float v0 = be, v1 = be;
#pragma unroll
            for (int c = 0; c < 4; ++c) {
                const float4 av = a[c], bv = b[c];
                v0 = fmaf(av.x, we[4 * c + 0], v0);
                v0 = fmaf(av.y, we[4 * c + 1], v0);
                v0 = fmaf(av.z, we[4 * c + 2], v0);
                v0 = fmaf(av.w, we[4 * c + 3], v0);
                v1 = fmaf(bv.x, we[4 * c + 0], v1);
                v1 = fmaf(bv.y, we[4 * c + 1], v1);
                v1 = fmaf(bv.z, we[4 * c + 2], v1);
                v1 = fmaf(bv.w, we[4 * c + 3], v1);
            }
            acc += fmaxf(xv0 + v0, 0.0f);
            acc += fmaxf(xv1 + v1, 0.0f);
        }
        if (e < e1) {
            const int i0 = eid[e];
            const int s0 = src[i0];
            const float4* a = (const float4*)(edge_attr + (size_t)i0 * EDIM);
            const float xv0 = x[(size_t)s0 * D + lane];
            float v0 = be;
#pragma unroll
            for (int c = 0; c < 4; ++c) {
                const float4 av = a[c];
                v0 = fmaf(av.x, we[4 * c + 0], v0);
                v0 = fmaf(av.y, we[4 * c + 1], v0);
                v0 = fmaf(av.z, we[4 * c + 2], v0);
                v0 = fmaf(av.w, we[4 * c + 3], v0);
            }
            acc += fmaxf(xv0 + v0, 0.0f);
        }

        const size_t off = (size_t)n * D + lane;
        h[off] = x[off] + acc;
    }
}

// ---------------------------------------------------------------------------
// Phase 5: node MLP. Weights staged in LDS (no register-array spill).
//   out = relu(h @ W1 + b1) @ W2 + b2  (in-place on h buffer)
// W1s[k*64+j]: for fixed k lanes read 64 consecutive floats -> 2 lanes/bank
// (free per m136). hbuf reads are same-address broadcasts.
// ---------------------------------------------------------------------------
__global__ __launch_bounds__(256) void mlp_kernel(
    const float* __restrict__ W1, const float* __restrict__ b1,
    const float* __restrict__ W2, const float* __restrict__ b2,
    float* inout, int N)
{
    __shared__ float W1s[D * D];
    __shared__ float W2s[D * D];
    __shared__ float hbuf[4][D];
    __shared__ float tbuf[4][D];

    const int t = threadIdx.x;
    const float4* w1v = (const float4*)W1;
    const float4* w2v = (const float4*)W2;
    float4* w1s = (float4*)W1s;
    float4* w2s = (float4*)W2s;
#pragma unroll
    for (int i = 0; i < 4; ++i) {
        w1s[t + i * 256] = w1v[t + i * 256];
        w2s[t + i * 256] = w2v[t + i * 256];
    }
    __syncthreads();

    const int lane = t & 63;
    const int wv   = t >> 6;
    const float b1v = b1[lane];
    const float b2v = b2[lane];

    // N % 4 == 0 -> every wave has a valid node; barriers uniform.
    for (int base = blockIdx.x * 4; base < N; base += gridDim.x * 4) {
        const int    node = base + wv;
        const size_t off  = (size_t)node * D + lane;

        hbuf[wv][lane] = inout[off];
        __syncthreads();

        float acc = b1v;
#pragma unroll
        for (int k = 0; k < D; k += 4) {
            const float4 hv = *(const float4*)(&hbuf[wv][k]);
            acc = fmaf(hv.x, W1s[(k + 0) * D + lane], acc);
            acc = fmaf(hv.y, W1s[(k + 1) * D + lane], acc);
            acc = fmaf(hv.z, W1s[(k + 2) * D + lane], acc);
            acc = fmaf(hv.w, W1s[(k + 3) * D + lane], acc);
        }
        tbuf[wv][lane] = fmaxf(acc, 0.0f);
        __syncthreads();

        float acc2 = b2v;
#pragma unroll
        for (int k = 0; k < D; k += 4) {
            const float4 tv = *(const float4*)(&tbuf[wv][k]);
            acc2 = fmaf(tv.x, W2s[(k + 0) * D + lane], acc2);
            acc2 = fmaf(tv.y, W2s[(k + 1) * D + lane], acc2);
            acc2 = fmaf(tv.z, W2s[(k + 2) * D + lane], acc2);
            acc2 = fmaf(tv.w, W2s[(k + 3) * D + lane], acc2);
        }
        inout[off] = acc2;
        __syncthreads();   // protect hbuf/tbuf reuse across iterations
    }
}

// ---------------------------------------------------------------------------
// d_ws layout (ints): cnt[N] | row_start[N+1] | cursor[N] | bsum[256] | eid[E]
// total ~7.6 MB. d_out doubles as the h buffer between gather and mlp.
// ---------------------------------------------------------------------------
extern "C" void kernel_launch(void* const* d_in, const int* in_sizes, int n_in,
                              void* d_out, int out_size, void* d_ws, size_t ws_size,
                              hipStream_t stream)
{
    const float* x      = (const float*)d_in[0];
    const int*   eidx   = (const int*)d_in[1];
    const float* eattr  = (const float*)d_in[2];
    const float* W_edge = (const float*)d_in[3];
    const float* b_edge = (const float*)d_in[4];
    const float* W1     = (const float*)d_in[5];
    const float* b1     = (const float*)d_in[6];
    const float* W2     = (const float*)d_in[7];
    const float* b2     = (const float*)d_in[8];
    float*       out    = (float*)d_out;

    const int E = in_sizes[1] / 2;      // 1,600,000
    const int N = in_sizes[0] / D;      // 100,000

    const int* src = eidx;
    const int* dst = eidx + E;

    int* cnt       = (int*)d_ws;
    int* row_start = cnt + N;           // N+1 entries
    int* cursor    = row_start + N + 1;
    int* bsum      = cursor + N;        // 256 entries
    int* eid       = bsum + 256;        // E entries

    const int nchunks = (N + CHUNK - 1) / CHUNK;   // 98 for N=100000

    hipMemsetAsync(cnt, 0, (size_t)N * sizeof(int), stream);
    hist_kernel<<<1024, 256, 0, stream>>>(dst, cnt, E);
    chunk_sum_kernel<<<nchunks, 256, 0, stream>>>(cnt, bsum, N);
    scan_chunksums_kernel<<<1, 256, 0, stream>>>(bsum, nchunks, row_start, N, E);
    chunk_scan_kernel<<<nchunks, 256, 0, stream>>>(cnt, bsum, row_start, cursor, N);
    scatter_kernel<<<1024, 256, 0, stream>>>(dst, cursor, eid, E);
    gather_kernel<<<4096, 256, 0, stream>>>(x, src, eattr, W_edge, b_edge,
                                            row_start, eid, out, N);
    mlp_kernel<<<2048, 256, 0, stream>>>(W1, b1, W2, b2, out, N);
}

// Round 3
// 680.697 us; speedup vs baseline: 1.0909x; 1.0909x over previous
//
#include <hip/hip_runtime.h>

#define D 64
#define EDIM 16
#define CHUNK 1024   // counts-scan chunk size

// ---------------------------------------------------------------------------
// Phase 1: histogram of dst  (cnt[d] = degree of node d)
// ---------------------------------------------------------------------------
__global__ __launch_bounds__(256) void hist_kernel(
    const int* __restrict__ dst, int* __restrict__ cnt, int E)
{
    int i = blockIdx.x * blockDim.x + threadIdx.x;
    int stride = gridDim.x * blockDim.x;
    for (; i < E; i += stride) atomicAdd(&cnt[dst[i]], 1);
}

// ---------------------------------------------------------------------------
// Phase 2a: per-chunk sums (CHUNK counts per block)
// ---------------------------------------------------------------------------
__global__ __launch_bounds__(256) void chunk_sum_kernel(
    const int* __restrict__ cnt, int* __restrict__ bsum, int N)
{
    __shared__ int red[256];
    const int base = blockIdx.x * CHUNK;
    const int t = threadIdx.x;
    int s = 0;
#pragma unroll
    for (int r = 0; r < 4; ++r) {
        int idx = base + t + r * 256;
        if (idx < N) s += cnt[idx];
    }
    red[t] = s; __syncthreads();
    for (int off = 128; off > 0; off >>= 1) {
        if (t < off) red[t] += red[t + off];
        __syncthreads();
    }
    if (t == 0) bsum[blockIdx.x] = red[0];
}

// ---------------------------------------------------------------------------
// Phase 2b: exclusive scan of chunk sums (single block; nchunks <= 256)
// ---------------------------------------------------------------------------
__global__ __launch_bounds__(256) void scan_chunksums_kernel(
    int* __restrict__ bsum, int nchunks, int* __restrict__ row_start,
    int N, int E)
{
    __shared__ int lds[256];
    const int t = threadIdx.x;
    const int v = (t < nchunks) ? bsum[t] : 0;
    lds[t] = v; __syncthreads();
    for (int off = 1; off < 256; off <<= 1) {
        int add = (t >= off) ? lds[t - off] : 0;
        __syncthreads();
        lds[t] += add;
        __syncthreads();
    }
    if (t < nchunks) bsum[t] = lds[t] - v;   // exclusive
    if (t == 0) row_start[N] = E;
}

// ---------------------------------------------------------------------------
// Phase 2c: per-chunk exclusive scan -> row_start (and cursor copy)
// ---------------------------------------------------------------------------
__global__ __launch_bounds__(256) void chunk_scan_kernel(
    const int* __restrict__ cnt, const int* __restrict__ bsum,
    int* __restrict__ row_start, int* __restrict__ cursor, int N)
{
    __shared__ int lds[256];
    const int base = blockIdx.x * CHUNK;
    const int t = threadIdx.x;
    int v[4]; int s = 0;
#pragma unroll
    for (int r = 0; r < 4; ++r) {
        int idx = base + t * 4 + r;
        v[r] = (idx < N) ? cnt[idx] : 0;
        s += v[r];
    }
    lds[t] = s; __syncthreads();
    for (int off = 1; off < 256; off <<= 1) {
        int add = (t >= off) ? lds[t - off] : 0;
        __syncthreads();
        lds[t] += add;
        __syncthreads();
    }
    int run = bsum[blockIdx.x] + (lds[t] - s);   // exclusive within grid
#pragma unroll
    for (int r = 0; r < 4; ++r) {
        int idx = base + t * 4 + r;
        if (idx < N) { row_start[idx] = run; cursor[idx] = run; }
        run += v[r];
    }
}

// ---------------------------------------------------------------------------
// Phase 3: payload reorder into CSR order. One QUAD (4 lanes) per edge:
//   p = cursor[dst[i]]++          (lane r==0, broadcast via shfl width 4)
//   ea_sorted[p][:]  = edge_attr[i][:]   (each lane moves one float4)
//   src_sorted[p]    = src[i]
// Wave reads 16 edges x 64 B = 1 KB contiguous; writes are scattered but each
// quad emits a full 64 B chunk via 4x dwordx4 -> line-granular.
// ---------------------------------------------------------------------------
__global__ __launch_bounds__(256) void reorder_kernel(
    const int*   __restrict__ dst,
    const int*   __restrict__ src,
    const float* __restrict__ edge_attr,
    int*         __restrict__ cursor,
    int*         __restrict__ src_sorted,
    float*       __restrict__ ea_sorted,
    int E)
{
    const int t = threadIdx.x;
    const int r = t & 3;                                   // lane-in-quad
    int i = (blockIdx.x * blockDim.x + t) >> 2;            // edge id
    const int ngroups = (gridDim.x * blockDim.x) >> 2;

    const float4* eav = (const float4*)edge_attr;
    float4*       esv = (float4*)ea_sorted;

    for (; i < E; i += ngroups) {
        int p = 0;
        if (r == 0) p = atomicAdd(&cursor[dst[i]], 1);
        p = __shfl(p, 0, 4);                               // quad broadcast
        const float4 v = eav[(size_t)i * 4 + r];           // 1KB/wave coalesced
        esv[(size_t)p * 4 + r] = v;                        // 64B/quad scattered
        if (r == 0) src_sorted[p] = src[i];
    }
}

// ---------------------------------------------------------------------------
// Phase 4: gather-aggregate, fully sequential edge streams.
// One wave per node; lane j owns column j.
//   h[n] = x[n] + sum_{e in [row_start[n],row_start[n+1])}
//                   relu(x[src_sorted[e]] + ea_sorted[e] @ W_edge + b_edge)
// ea_sorted/src_sorted reads are sequential (L2-prefetch friendly); only the
// x-row gather is random (x = 25.6 MB, L2/L3-served). 4-edge ILP hides it.
// ---------------------------------------------------------------------------
__global__ __launch_bounds__(256) void gather_kernel(
    const float* __restrict__ x,
    const int*   __restrict__ src_sorted,
    const float* __restrict__ ea_sorted,
    const float* __restrict__ W_edge,
    const float* __restrict__ b_edge,
    const int*   __restrict__ row_start,
    float*       __restrict__ h,
    int N)
{
    const int lane   = threadIdx.x & 63;
    const int wave   = blockIdx.x * 4 + (threadIdx.x >> 6);
    const int nwaves = gridDim.x * 4;

    float we[EDIM];
#pragma unroll
    for (int k = 0; k < EDIM; ++k) we[k] = W_edge[k * D + lane];
    const float be = b_edge[lane];

    for (int n = wave; n < N; n += nwaves) {
        const int e0 = row_start[n];
        const int e1 = row_start[n + 1];
        float acc = 0.0f;

        int e = e0;
        for (; e + 4 <= e1; e += 4) {
            int s[4];
#pragma unroll
            for (int u = 0; u < 4; ++u) s[u] = src_sorted[e + u];
            float xv[4];
#pragma unroll
            for (int u = 0; u < 4; ++u) xv[u] = x[(size_t)s[u] * D + lane];
            float v[4];
#pragma unroll
            for (int u = 0; u < 4; ++u) {
                const float4* a = (const float4*)(ea_sorted + (size_t)(e + u) * EDIM);
                float vv = be;
#pragma unroll
                for (int c = 0; c < 4; ++c) {
                    const float4 av = a[c];
                    vv = fmaf(av.x, we[4 * c + 0], vv);
                    vv = fmaf(av.y, we[4 * c + 1], vv);
                    vv = fmaf(av.z, we[4 * c + 2], vv);
                    vv = fmaf(av.w, we[4 * c + 3], vv);
                }
                v[u] = vv;
            }
#pragma unroll
            for (int u = 0; u < 4; ++u) acc += fmaxf(xv[u] + v[u], 0.0f);
        }
        for (; e < e1; ++e) {
            const int s0 = src_sorted[e];
            const float4* a = (const float4*)(ea_sorted + (size_t)e * EDIM);
            const float xv0 = x[(size_t)s0 * D + lane];
            float v0 = be;
#pragma unroll
            for (int c = 0; c < 4; ++c) {
                const float4 av = a[c];
                v0 = fmaf(av.x, we[4 * c + 0], v0);
                v0 = fmaf(av.y, we[4 * c + 1], v0);
                v0 = fmaf(av.z, we[4 * c + 2], v0);
                v0 = fmaf(av.w, we[4 * c + 3], v0);
            }
            acc += fmaxf(xv0 + v0, 0.0f);
        }

        const size_t off = (size_t)n * D + lane;
        h[off] = x[off] + acc;
    }
}

// ---------------------------------------------------------------------------
// Phase 5: node MLP, weights in LDS.  out = relu(h@W1+b1)@W2+b2, in place.
// ---------------------------------------------------------------------------
__global__ __launch_bounds__(256) void mlp_kernel(
    const float* __restrict__ W1, const float* __restrict__ b1,
    const float* __restrict__ W2, const float* __restrict__ b2,
    float* inout, int N)
{
    __shared__ float W1s[D * D];
    __shared__ float W2s[D * D];
    __shared__ float hbuf[4][D];
    __shared__ float tbuf[4][D];

    const int t = threadIdx.x;
    const float4* w1v = (const float4*)W1;
    const float4* w2v = (const float4*)W2;
    float4* w1s = (float4*)W1s;
    float4* w2s = (float4*)W2s;
#pragma unroll
    for (int i = 0; i < 4; ++i) {
        w1s[t + i * 256] = w1v[t + i * 256];
        w2s[t + i * 256] = w2v[t + i * 256];
    }
    __syncthreads();

    const int lane = t & 63;
    const int wv   = t >> 6;
    const float b1v = b1[lane];
    const float b2v = b2[lane];

    for (int base = blockIdx.x * 4; base < N; base += gridDim.x * 4) {
        const int    node = base + wv;
        const size_t off  = (size_t)node * D + lane;

        hbuf[wv][lane] = inout[off];
        __syncthreads();

        float acc = b1v;
#pragma unroll
        for (int k = 0; k < D; k += 4) {
            const float4 hv = *(const float4*)(&hbuf[wv][k]);
            acc = fmaf(hv.x, W1s[(k + 0) * D + lane], acc);
            acc = fmaf(hv.y, W1s[(k + 1) * D + lane], acc);
            acc = fmaf(hv.z, W1s[(k + 2) * D + lane], acc);
            acc = fmaf(hv.w, W1s[(k + 3) * D + lane], acc);
        }
        tbuf[wv][lane] = fmaxf(acc, 0.0f);
        __syncthreads();

        float acc2 = b2v;
#pragma unroll
        for (int k = 0; k < D; k += 4) {
            const float4 tv = *(const float4*)(&tbuf[wv][k]);
            acc2 = fmaf(tv.x, W2s[(k + 0) * D + lane], acc2);
            acc2 = fmaf(tv.y, W2s[(k + 1) * D + lane], acc2);
            acc2 = fmaf(tv.z, W2s[(k + 2) * D + lane], acc2);
            acc2 = fmaf(tv.w, W2s[(k + 3) * D + lane], acc2);
        }
        inout[off] = acc2;
        __syncthreads();   // protect hbuf/tbuf reuse across iterations
    }
}

// ---------------------------------------------------------------------------
// Fallback edge kernel (R1, atomic scatter) — used only if ws_size is too
// small for the sorted-payload workspace. Deterministic branch on ws_size.
// ---------------------------------------------------------------------------
__global__ __launch_bounds__(256) void edge_atomic_kernel(
    const float* __restrict__ x,
    const int*   __restrict__ src,
    const int*   __restrict__ dst,
    const float* __restrict__ edge_attr,
    const float* __restrict__ W_edge,
    const float* __restrict__ b_edge,
    float*       __restrict__ aggr,
    int E)
{
    const int lane   = threadIdx.x & 63;
    const int wave   = blockIdx.x * 4 + (threadIdx.x >> 6);
    const int nwaves = gridDim.x * 4;

    float we[EDIM];
#pragma unroll
    for (int k = 0; k < EDIM; ++k) we[k] = W_edge[k * D + lane];
    const float be = b_edge[lane];

    for (int i = wave; i < E; i += nwaves) {
        const int s = src[i];
        const int d = dst[i];
        const float4* eap = (const float4*)(edge_attr + (size_t)i * EDIM);
        float acc = be;
#pragma unroll
        for (int c = 0; c < 4; ++c) {
            const float4 ea = eap[c];
            acc = fmaf(ea.x, we[4 * c + 0], acc);
            acc = fmaf(ea.y, we[4 * c + 1], acc);
            acc = fmaf(ea.z, we[4 * c + 2], acc);
            acc = fmaf(ea.w, we[4 * c + 3], acc);
        }
        float m = fmaxf(x[(size_t)s * D + lane] + acc, 0.0f);
        atomicAdd(&aggr[(size_t)d * D + lane], m);
    }
}

__global__ __launch_bounds__(256) void add_x_kernel(
    const float* __restrict__ x, float* __restrict__ h, size_t n)
{
    size_t i = (size_t)blockIdx.x * blockDim.x + threadIdx.x;
    size_t stride = (size_t)gridDim.x * blockDim.x;
    for (; i < n; i += stride) h[i] += x[i];
}

// ---------------------------------------------------------------------------
// d_ws layout (4-byte units):
//   cnt[N] | row_start[N+1] | cursor[N] | bsum[256] | src_sorted[E] |
//   ea_sorted[E*16]
// total ~110 MB. d_out doubles as the h buffer between gather and mlp.
// ---------------------------------------------------------------------------
extern "C" void kernel_launch(void* const* d_in, const int* in_sizes, int n_in,
                              void* d_out, int out_size, void* d_ws, size_t ws_size,
                              hipStream_t stream)
{
    const float* x      = (const float*)d_in[0];
    const int*   eidx   = (const int*)d_in[1];
    const float* eattr  = (const float*)d_in[2];
    const float* W_edge = (const float*)d_in[3];
    const float* b_edge = (const float*)d_in[4];
    const float* W1     = (const float*)d_in[5];
    const float* b1     = (const float*)d_in[6];
    const float* W2     = (const float*)d_in[7];
    const float* b2     = (const float*)d_in[8];
    float*       out    = (float*)d_out;

    const int E = in_sizes[1] / 2;      // 1,600,000
    const int N = in_sizes[0] / D;      // 100,000

    const int* src = eidx;
    const int* dst = eidx + E;

    const size_t need = (size_t)(3 * N + 1 + 256 + E) * 4 + (size_t)E * EDIM * 4;

    if (ws_size >= need) {
        int*   cnt        = (int*)d_ws;
        int*   row_start  = cnt + N;            // N+1 entries
        int*   cursor     = row_start + N + 1;
        int*   bsum       = cursor + N;         // 256 entries
        int*   src_sorted = bsum + 256;         // E entries
        float* ea_sorted  = (float*)(src_sorted + E);   // E*16 floats

        const int nchunks = (N + CHUNK - 1) / CHUNK;    // 98

        hipMemsetAsync(cnt, 0, (size_t)N * sizeof(int), stream);
        hist_kernel<<<1024, 256, 0, stream>>>(dst, cnt, E);
        chunk_sum_kernel<<<nchunks, 256, 0, stream>>>(cnt, bsum, N);
        scan_chunksums_kernel<<<1, 256, 0, stream>>>(bsum, nchunks, row_start, N, E);
        chunk_scan_kernel<<<nchunks, 256, 0, stream>>>(cnt, bsum, row_start, cursor, N);
        reorder_kernel<<<2048, 256, 0, stream>>>(dst, src, eattr, cursor,
                                                 src_sorted, ea_sorted, E);
        gather_kernel<<<4096, 256, 0, stream>>>(x, src_sorted, ea_sorted,
                                                W_edge, b_edge, row_start, out, N);
        mlp_kernel<<<2048, 256, 0, stream>>>(W1, b1, W2, b2, out, N);
    } else {
        // Fallback: R1 atomic path.
        hipMemsetAsync(out, 0, (size_t)N * D * sizeof(float), stream);
        edge_atomic_kernel<<<2048, 256, 0, stream>>>(x, src, dst, eattr,
                                                     W_edge, b_edge, out, E);
        add_x_kernel<<<1024, 256, 0, stream>>>(x, out, (size_t)N * D);
        mlp_kernel<<<2048, 256, 0, stream>>>(W1, b1, W2, b2, out, N);
    }
}

// Round 4
// 561.804 us; speedup vs baseline: 1.3218x; 1.2116x over previous
//
#include <hip/hip_runtime.h>

#define D 64
#define EDIM 16
#define CHUNK 1024   // counts-scan chunk size

// ---------------------------------------------------------------------------
// Phase 1: histogram of dst  (cnt[d] = degree of node d)
// ---------------------------------------------------------------------------
__global__ __launch_bounds__(256) void hist_kernel(
    const int* __restrict__ dst, int* __restrict__ cnt, int E)
{
    int i = blockIdx.x * blockDim.x + threadIdx.x;
    int stride = gridDim.x * blockDim.x;
    for (; i < E; i += stride) atomicAdd(&cnt[dst[i]], 1);
}

// ---------------------------------------------------------------------------
// Phase 2a: per-chunk sums (CHUNK counts per block)
// ---------------------------------------------------------------------------
__global__ __launch_bounds__(256) void chunk_sum_kernel(
    const int* __restrict__ cnt, int* __restrict__ bsum, int N)
{
    __shared__ int red[256];
    const int base = blockIdx.x * CHUNK;
    const int t = threadIdx.x;
    int s = 0;
#pragma unroll
    for (int r = 0; r < 4; ++r) {
        int idx = base + t + r * 256;
        if (idx < N) s += cnt[idx];
    }
    red[t] = s; __syncthreads();
    for (int off = 128; off > 0; off >>= 1) {
        if (t < off) red[t] += red[t + off];
        __syncthreads();
    }
    if (t == 0) bsum[blockIdx.x] = red[0];
}

// ---------------------------------------------------------------------------
// Phase 2b: exclusive scan of chunk sums (single block; nchunks <= 256)
// ---------------------------------------------------------------------------
__global__ __launch_bounds__(256) void scan_chunksums_kernel(
    int* __restrict__ bsum, int nchunks, int* __restrict__ row_start,
    int N, int E)
{
    __shared__ int lds[256];
    const int t = threadIdx.x;
    const int v = (t < nchunks) ? bsum[t] : 0;
    lds[t] = v; __syncthreads();
    for (int off = 1; off < 256; off <<= 1) {
        int add = (t >= off) ? lds[t - off] : 0;
        __syncthreads();
        lds[t] += add;
        __syncthreads();
    }
    if (t < nchunks) bsum[t] = lds[t] - v;   // exclusive
    if (t == 0) row_start[N] = E;
}

// ---------------------------------------------------------------------------
// Phase 2c: per-chunk exclusive scan -> row_start (and cursor copy)
// ---------------------------------------------------------------------------
__global__ __launch_bounds__(256) void chunk_scan_kernel(
    const int* __restrict__ cnt, const int* __restrict__ bsum,
    int* __restrict__ row_start, int* __restrict__ cursor, int N)
{
    __shared__ int lds[256];
    const int base = blockIdx.x * CHUNK;
    const int t = threadIdx.x;
    int v[4]; int s = 0;
#pragma unroll
    for (int r = 0; r < 4; ++r) {
        int idx = base + t * 4 + r;
        v[r] = (idx < N) ? cnt[idx] : 0;
        s += v[r];
    }
    lds[t] = s; __syncthreads();
    for (int off = 1; off < 256; off <<= 1) {
        int add = (t >= off) ? lds[t - off] : 0;
        __syncthreads();
        lds[t] += add;
        __syncthreads();
    }
    int run = bsum[blockIdx.x] + (lds[t] - s);   // exclusive within grid
#pragma unroll
    for (int r = 0; r < 4; ++r) {
        int idx = base + t * 4 + r;
        if (idx < N) { row_start[idx] = run; cursor[idx] = run; }
        run += v[r];
    }
}

// ---------------------------------------------------------------------------
// Phase 3: payload reorder into CSR order. One QUAD (4 lanes) per edge.
// ---------------------------------------------------------------------------
__global__ __launch_bounds__(256) void reorder_kernel(
    const int*   __restrict__ dst,
    const int*   __restrict__ src,
    const float* __restrict__ edge_attr,
    int*         __restrict__ cursor,
    int*         __restrict__ src_sorted,
    float*       __restrict__ ea_sorted,
    int E)
{
    const int t = threadIdx.x;
    const int r = t & 3;                                   // lane-in-quad
    int i = (blockIdx.x * blockDim.x + t) >> 2;            // edge id
    const int ngroups = (gridDim.x * blockDim.x) >> 2;

    const float4* eav = (const float4*)edge_attr;
    float4*       esv = (float4*)ea_sorted;

    for (; i < E; i += ngroups) {
        int p = 0;
        if (r == 0) p = atomicAdd(&cursor[dst[i]], 1);
        p = __shfl(p, 0, 4);                               // quad broadcast
        const float4 v = eav[(size_t)i * 4 + r];           // 1KB/wave coalesced
        esv[(size_t)p * 4 + r] = v;                        // 64B/quad scattered
        if (r == 0) src_sorted[p] = src[i];
    }
}

// ---------------------------------------------------------------------------
// Phase 4: gather-aggregate with 16-lane edge groups for 4x memory-level
// parallelism per instruction.
//   lane = u*16 + c :  u = edge slot (0..3), c = column quad (cols 4c..4c+3)
// Per iteration, ONE x-load instruction fetches 4 independent rows and each
// of the 4 ea-load instructions fetches 4 independent 16B chunks.
// Tail edges are clamped + masked via fmaf(msg, mask, acc).
// Cross-group reduce: __shfl_xor 16/32; group 0 adds x[n] and writes the row.
// ---------------------------------------------------------------------------
__global__ __launch_bounds__(256) void gather_kernel(
    const float* __restrict__ x,
    const int*   __restrict__ src_sorted,
    const float* __restrict__ ea_sorted,
    const float* __restrict__ W_edge,
    const float* __restrict__ b_edge,
    const int*   __restrict__ row_start,
    float*       __restrict__ h,
    int N)
{
    const int lane = threadIdx.x & 63;
    const int u    = lane >> 4;      // edge slot in group-of-4
    const int c    = lane & 15;      // column quad
    const int wave   = blockIdx.x * 4 + (threadIdx.x >> 6);
    const int nwaves = gridDim.x * 4;

    // W_edge quad-column: we[k] = W_edge[k][4c..4c+3]  (64 VGPRs)
    float4 we[EDIM];
#pragma unroll
    for (int k = 0; k < EDIM; ++k)
        we[k] = *(const float4*)(W_edge + k * D + 4 * c);
    const float4 be = *(const float4*)(b_edge + 4 * c);

    for (int n = wave; n < N; n += nwaves) {
        const int e0 = row_start[n];
        const int e1 = row_start[n + 1];
        float4 acc = make_float4(0.0f, 0.0f, 0.0f, 0.0f);

        for (int e = e0; e < e1; e += 4) {
            const int  ee  = e + u;
            const bool ok  = ee < e1;
            const int  ec  = ok ? ee : (e1 - 1);        // clamp (e1>=1 here)
            const float msk = ok ? 1.0f : 0.0f;

            const int    s  = src_sorted[ec];
            const float4 xv = *(const float4*)(x + (size_t)s * D + 4 * c);

            const float4* a = (const float4*)(ea_sorted + (size_t)ec * EDIM);
            const float4 a0 = a[0], a1 = a[1], a2 = a[2], a3 = a[3];
            const float av[EDIM] = {a0.x, a0.y, a0.z, a0.w,
                                    a1.x, a1.y, a1.z, a1.w,
                                    a2.x, a2.y, a2.z, a2.w,
                                    a3.x, a3.y, a3.z, a3.w};
            float4 v = be;
#pragma unroll
            for (int k = 0; k < EDIM; ++k) {
                v.x = fmaf(av[k], we[k].x, v.x);
                v.y = fmaf(av[k], we[k].y, v.y);
                v.z = fmaf(av[k], we[k].z, v.z);
                v.w = fmaf(av[k], we[k].w, v.w);
            }
            const float mx = fmaxf(xv.x + v.x, 0.0f);
            const float my = fmaxf(xv.y + v.y, 0.0f);
            const float mz = fmaxf(xv.z + v.z, 0.0f);
            const float mw = fmaxf(xv.w + v.w, 0.0f);
            acc.x = fmaf(mx, msk, acc.x);
            acc.y = fmaf(my, msk, acc.y);
            acc.z = fmaf(mz, msk, acc.z);
            acc.w = fmaf(mw, msk, acc.w);
        }

        // reduce across the 4 edge slots (lane bits 4 and 5)
#pragma unroll
        for (int off = 16; off < 64; off <<= 1) {
            acc.x += __shfl_xor(acc.x, off, 64);
            acc.y += __shfl_xor(acc.y, off, 64);
            acc.z += __shfl_xor(acc.z, off, 64);
            acc.w += __shfl_xor(acc.w, off, 64);
        }

        if (u == 0) {
            const float4 xn = *(const float4*)(x + (size_t)n * D + 4 * c);
            float4 o;
            o.x = xn.x + acc.x;
            o.y = xn.y + acc.y;
            o.z = xn.z + acc.z;
            o.w = xn.w + acc.w;
            *(float4*)(h + (size_t)n * D + 4 * c) = o;
        }
    }
}

// ---------------------------------------------------------------------------
// Phase 5: node MLP, weights in LDS.  out = relu(h@W1+b1)@W2+b2, in place.
// ---------------------------------------------------------------------------
__global__ __launch_bounds__(256) void mlp_kernel(
    const float* __restrict__ W1, const float* __restrict__ b1,
    const float* __restrict__ W2, const float* __restrict__ b2,
    float* inout, int N)
{
    __shared__ float W1s[D * D];
    __shared__ float W2s[D * D];
    __shared__ float hbuf[4][D];
    __shared__ float tbuf[4][D];

    const int t = threadIdx.x;
    const float4* w1v = (const float4*)W1;
    const float4* w2v = (const float4*)W2;
    float4* w1s = (float4*)W1s;
    float4* w2s = (float4*)W2s;
#pragma unroll
    for (int i = 0; i < 4; ++i) {
        w1s[t + i * 256] = w1v[t + i * 256];
        w2s[t + i * 256] = w2v[t + i * 256];
    }
    __syncthreads();

    const int lane = t & 63;
    const int wv   = t >> 6;
    const float b1v = b1[lane];
    const float b2v = b2[lane];

    for (int base = blockIdx.x * 4; base < N; base += gridDim.x * 4) {
        const int    node = base + wv;
        const size_t off  = (size_t)node * D + lane;

        hbuf[wv][lane] = inout[off];
        __syncthreads();

        float acc = b1v;
#pragma unroll
        for (int k = 0; k < D; k += 4) {
            const float4 hv = *(const float4*)(&hbuf[wv][k]);
            acc = fmaf(hv.x, W1s[(k + 0) * D + lane], acc);
            acc = fmaf(hv.y, W1s[(k + 1) * D + lane], acc);
            acc = fmaf(hv.z, W1s[(k + 2) * D + lane], acc);
            acc = fmaf(hv.w, W1s[(k + 3) * D + lane], acc);
        }
        tbuf[wv][lane] = fmaxf(acc, 0.0f);
        __syncthreads();

        float acc2 = b2v;
#pragma unroll
        for (int k = 0; k < D; k += 4) {
            const float4 tv = *(const float4*)(&tbuf[wv][k]);
            acc2 = fmaf(tv.x, W2s[(k + 0) * D + lane], acc2);
            acc2 = fmaf(tv.y, W2s[(k + 1) * D + lane], acc2);
            acc2 = fmaf(tv.z, W2s[(k + 2) * D + lane], acc2);
            acc2 = fmaf(tv.w, W2s[(k + 3) * D + lane], acc2);
        }
        inout[off] = acc2;
        __syncthreads();   // protect hbuf/tbuf reuse across iterations
    }
}

// ---------------------------------------------------------------------------
// Fallback edge kernel (atomic scatter) — only if ws_size too small.
// ---------------------------------------------------------------------------
__global__ __launch_bounds__(256) void edge_atomic_kernel(
    const float* __restrict__ x,
    const int*   __restrict__ src,
    const int*   __restrict__ dst,
    const float* __restrict__ edge_attr,
    const float* __restrict__ W_edge,
    const float* __restrict__ b_edge,
    float*       __restrict__ aggr,
    int E)
{
    const int lane   = threadIdx.x & 63;
    const int wave   = blockIdx.x * 4 + (threadIdx.x >> 6);
    const int nwaves = gridDim.x * 4;

    float we[EDIM];
#pragma unroll
    for (int k = 0; k < EDIM; ++k) we[k] = W_edge[k * D + lane];
    const float be = b_edge[lane];

    for (int i = wave; i < E; i += nwaves) {
        const int s = src[i];
        const int d = dst[i];
        const float4* eap = (const float4*)(edge_attr + (size_t)i * EDIM);
        float acc = be;
#pragma unroll
        for (int c = 0; c < 4; ++c) {
            const float4 ea = eap[c];
            acc = fmaf(ea.x, we[4 * c + 0], acc);
            acc = fmaf(ea.y, we[4 * c + 1], acc);
            acc = fmaf(ea.z, we[4 * c + 2], acc);
            acc = fmaf(ea.w, we[4 * c + 3], acc);
        }
        float m = fmaxf(x[(size_t)s * D + lane] + acc, 0.0f);
        atomicAdd(&aggr[(size_t)d * D + lane], m);
    }
}

__global__ __launch_bounds__(256) void add_x_kernel(
    const float* __restrict__ x, float* __restrict__ h, size_t n)
{
    size_t i = (size_t)blockIdx.x * blockDim.x + threadIdx.x;
    size_t stride = (size_t)gridDim.x * blockDim.x;
    for (; i < n; i += stride) h[i] += x[i];
}

// ---------------------------------------------------------------------------
// d_ws layout (4-byte units):
//   cnt[N] | row_start[N+1] | cursor[N] | bsum[256] | src_sorted[E] |
//   ea_sorted[E*16]   (~110 MB total)
// ---------------------------------------------------------------------------
extern "C" void kernel_launch(void* const* d_in, const int* in_sizes, int n_in,
                              void* d_out, int out_size, void* d_ws, size_t ws_size,
                              hipStream_t stream)
{
    const float* x      = (const float*)d_in[0];
    const int*   eidx   = (const int*)d_in[1];
    const float* eattr  = (const float*)d_in[2];
    const float* W_edge = (const float*)d_in[3];
    const float* b_edge = (const float*)d_in[4];
    const float* W1     = (const float*)d_in[5];
    const float* b1     = (const float*)d_in[6];
    const float* W2     = (const float*)d_in[7];
    const float* b2     = (const float*)d_in[8];
    float*       out    = (float*)d_out;

    const int E = in_sizes[1] / 2;      // 1,600,000
    const int N = in_sizes[0] / D;      // 100,000

    const int* src = eidx;
    const int* dst = eidx + E;

    const size_t need = (size_t)(3 * N + 1 + 256 + E) * 4 + (size_t)E * EDIM * 4;

    if (ws_size >= need) {
        int*   cnt        = (int*)d_ws;
        int*   row_start  = cnt + N;            // N+1 entries
        int*   cursor     = row_start + N + 1;
        int*   bsum       = cursor + N;         // 256 entries
        int*   src_sorted = bsum + 256;         // E entries
        float* ea_sorted  = (float*)(src_sorted + E);   // E*16 floats

        const int nchunks = (N + CHUNK - 1) / CHUNK;    // 98

        hipMemsetAsync(cnt, 0, (size_t)N * sizeof(int), stream);
        hist_kernel<<<2048, 256, 0, stream>>>(dst, cnt, E);
        chunk_sum_kernel<<<nchunks, 256, 0, stream>>>(cnt, bsum, N);
        scan_chunksums_kernel<<<1, 256, 0, stream>>>(bsum, nchunks, row_start, N, E);
        chunk_scan_kernel<<<nchunks, 256, 0, stream>>>(cnt, bsum, row_start, cursor, N);
        reorder_kernel<<<4096, 256, 0, stream>>>(dst, src, eattr, cursor,
                                                 src_sorted, ea_sorted, E);
        gather_kernel<<<4096, 256, 0, stream>>>(x, src_sorted, ea_sorted,
                                                W_edge, b_edge, row_start, out, N);
        mlp_kernel<<<2048, 256, 0, stream>>>(W1, b1, W2, b2, out, N);
    } else {
        // Fallback: atomic path.
        hipMemsetAsync(out, 0, (size_t)N * D * sizeof(float), stream);
        edge_atomic_kernel<<<2048, 256, 0, stream>>>(x, src, dst, eattr,
                                                     W_edge, b_edge, out, E);
        add_x_kernel<<<1024, 256, 0, stream>>>(x, out, (size_t)N * D);
        mlp_kernel<<<2048, 256, 0, stream>>>(W1, b1, W2, b2, out, N);
    }
}